// Round 19
// baseline (92.714 us; speedup 1.0000x reference)
//
#include <hip/hip_runtime.h>
#include <hip/hip_bf16.h>

typedef __bf16 bf16_t;
typedef bf16_t bf16x8 __attribute__((ext_vector_type(8)));
typedef bf16_t bf16x4 __attribute__((ext_vector_type(4)));
typedef float  f32x4  __attribute__((ext_vector_type(4)));
typedef float  f32x16 __attribute__((ext_vector_type(16)));

__device__ __forceinline__ f32x4 mfma16(bf16x8 a, bf16x8 b, f32x4 c) {
  return __builtin_amdgcn_mfma_f32_16x16x32_bf16(a, b, c, 0, 0, 0);
}
__device__ __forceinline__ f32x16 mfma32(bf16x8 a, bf16x8 b, f32x16 c) {
  return __builtin_amdgcn_mfma_f32_32x32x16_bf16(a, b, c, 0, 0, 0);
}

// ---------------- fused cast f32 -> bf16 for all 5 tensors ----------------
__global__ __launch_bounds__(256) void cast_all_k(const float* __restrict__ f,
                                                  const float* __restrict__ wq,
                                                  const float* __restrict__ wk,
                                                  const float* __restrict__ wv,
                                                  const float* __restrict__ wo,
                                                  bf16_t* __restrict__ Xbf,
                                                  bf16_t* __restrict__ Wqkv,
                                                  bf16_t* __restrict__ Wo) {
  int i = blockIdx.x * 256 + threadIdx.x;
  const float* src; bf16_t* dst; int off;
  if (i < 1048576)      { src = f;  dst = Xbf;                 off = 0; }
  else if (i < 1310720) { src = wq; dst = Wqkv;                off = 1048576; }
  else if (i < 1376256) { src = wk; dst = Wqkv + 1024 * 1024;  off = 1310720; }
  else if (i < 1441792) { src = wv; dst = Wqkv + 1280 * 1024;  off = 1376256; }
  else if (i < 1703936) { src = wo; dst = Wo;                  off = 1441792; }
  else return;
  int j = i - off;
  float4 v = reinterpret_cast<const float4*>(src)[j];
  bf16x4 o = { (bf16_t)v.x, (bf16_t)v.y, (bf16_t)v.z, (bf16_t)v.w };
  reinterpret_cast<bf16x4*>(dst)[j] = o;
}

// ---------------- GEMM: C[M,N] = A[M,K] * B[N,K]^T, bf16 in, CT out -------------
// BM x 128 tile, BK=64, 4 waves, 16x16x32 MFMA, double-buffered LDS with
// COUNTED-vmcnt pipeline (T4). BM=128 (MR=4): 2x A-reuse per ds_read, m103's
// best tile for this structure; pipeline removes the old barrier-drain penalty.
template<int BM, typename CT>
__global__ __launch_bounds__(256) void gemm_bt(const bf16_t* __restrict__ A,
                                               const bf16_t* __restrict__ B,
                                               CT* __restrict__ C,
                                               int M, int N, int K) {
  constexpr int MR = BM / 32;                     // acc rows per wave
  __shared__ __align__(16) unsigned short sA[2][BM * 64];
  __shared__ __align__(16) unsigned short sB[2][128 * 64];
  const int tid = threadIdx.x;
  const int lane = tid & 63;
  const int wid = tid >> 6;
  const int wm = wid >> 1, wn = wid & 1;
  const int lr = lane & 15, lg = lane >> 4;
  const int m0 = blockIdx.y * BM, n0 = blockIdx.x * 128;

  f32x4 acc[MR][4] = {};

  auto STAGE = [&](int buf, int k0) {             // BM/32+4 global_load_lds per wave
#pragma unroll
    for (int r = 0; r < BM / 32; ++r) {
      int e = r * 2048 + tid * 8;
      int row = e >> 6;
      int cc = ((e >> 3) & 7) ^ (row & 7);
      const bf16_t* ga = A + (size_t)(m0 + row) * K + k0 + cc * 8;
      __builtin_amdgcn_global_load_lds(
          (const __attribute__((address_space(1))) void*)ga,
          (__attribute__((address_space(3))) void*)(&sA[buf][r * 2048 + wid * 512]), 16, 0, 0);
    }
#pragma unroll
    for (int r = 0; r < 4; ++r) {
      int e = r * 2048 + tid * 8;
      int row = e >> 6;
      int cc = ((e >> 3) & 7) ^ (row & 7);
      const bf16_t* gb = B + (size_t)(n0 + row) * K + k0 + cc * 8;
      __builtin_amdgcn_global_load_lds(
          (const __attribute__((address_space(1))) void*)gb,
          (__attribute__((address_space(3))) void*)(&sB[buf][r * 2048 + wid * 512]), 16, 0, 0);
    }
  };

  const int nt = K >> 6;
  STAGE(0, 0);
  if (nt > 1) STAGE(1, 64);
  for (int t = 0; t < nt; ++t) {
    if (t < nt - 1) {
      if constexpr (BM == 128) asm volatile("s_waitcnt vmcnt(8)" ::: "memory");
      else                     asm volatile("s_waitcnt vmcnt(6)" ::: "memory");
    } else {
      asm volatile("s_waitcnt vmcnt(0)" ::: "memory");
    }
    asm volatile("s_barrier" ::: "memory");
    __builtin_amdgcn_sched_barrier(0);
    const int cur = t & 1;
#pragma unroll
    for (int ks = 0; ks < 2; ++ks) {
      bf16x8 afr[MR], bfr[4];
#pragma unroll
      for (int m = 0; m < MR; ++m) {
        int row = wm * (BM / 2) + m * 16 + lr;
        int sc = (ks * 4 + lg) ^ (row & 7);
        afr[m] = *reinterpret_cast<const bf16x8*>(&sA[cur][row * 64 + sc * 8]);
      }
#pragma unroll
      for (int n = 0; n < 4; ++n) {
        int row = wn * 64 + n * 16 + lr;
        int sc = (ks * 4 + lg) ^ (row & 7);
        bfr[n] = *reinterpret_cast<const bf16x8*>(&sB[cur][row * 64 + sc * 8]);
      }
#pragma unroll
      for (int m = 0; m < MR; ++m)
#pragma unroll
        for (int n = 0; n < 4; ++n)
          acc[m][n] = mfma16(afr[m], bfr[n], acc[m][n]);
    }
    asm volatile("s_barrier" ::: "memory");
    if (t + 2 < nt) STAGE(cur, (t + 2) << 6);
  }
#pragma unroll
  for (int m = 0; m < MR; ++m)
#pragma unroll
    for (int n = 0; n < 4; ++n) {
      int row = m0 + wm * (BM / 2) + m * 16 + lg * 4;
      int col = n0 + wn * 64 + n * 16 + lr;
#pragma unroll
      for (int r2 = 0; r2 < 4; ++r2)
        C[(size_t)(row + r2) * N + col] = (CT)acc[m][n][r2];
    }
}

// ---------------- merged RMSNorm + V-transpose (independent consumers of QKVr) ---
__global__ __launch_bounds__(256) void norm_trans_k(const bf16_t* __restrict__ qkv,
                                                    const float* __restrict__ qw,
                                                    const float* __restrict__ kw,
                                                    bf16_t* __restrict__ qn,
                                                    bf16_t* __restrict__ kn,
                                                    bf16_t* __restrict__ vt) {
  __shared__ float t[64][65];
  const int tid = threadIdx.x;
  if (blockIdx.x < 4096) {
    const int row = blockIdx.x;
    const int b = row >> 11, s = row & 2047;
    const bf16_t* rp = qkv + (size_t)row * 1536;
    bf16x4 qb = *reinterpret_cast<const bf16x4*>(rp + tid * 4);
    float q0 = (float)qb[0], q1 = (float)qb[1], q2 = (float)qb[2], q3 = (float)qb[3];
    float kv1 = (float)rp[1024 + tid];
    float sq = q0 * q0 + q1 * q1 + q2 * q2 + q3 * q3;
    float sk = kv1 * kv1;
#pragma unroll
    for (int d = 1; d < 64; d <<= 1) {
      sq += __shfl_xor(sq, d, 64);
      sk += __shfl_xor(sk, d, 64);
    }
    if ((tid & 63) == 0) { t[0][tid >> 6] = sq; t[0][4 + (tid >> 6)] = sk; }
    __syncthreads();
    sq = t[0][0] + t[0][1] + t[0][2] + t[0][3];
    sk = t[0][4] + t[0][5] + t[0][6] + t[0][7];
    const float rq = rsqrtf(sq * (1.0f / 1024.0f) + 1e-6f);
    const float rk = rsqrtf(sk * (1.0f / 256.0f) + 1e-6f);
    float4 w4 = *reinterpret_cast<const float4*>(qw + tid * 4);
    const int c = tid * 4, hh = c >> 6, d0 = c & 63;
    bf16x4 o = { (bf16_t)(q0 * rq * w4.x), (bf16_t)(q1 * rq * w4.y),
                 (bf16_t)(q2 * rq * w4.z), (bf16_t)(q3 * rq * w4.w) };
    *reinterpret_cast<bf16x4*>(qn + ((size_t)((b * 16 + hh) * 2048 + s)) * 64 + d0) = o;
    const int kvh = tid >> 6, dk = tid & 63;
    kn[((size_t)((b * 4 + kvh) * 2048 + s)) * 64 + dk] = (bf16_t)(kv1 * rk * kw[tid]);
  } else {
    const int idx = blockIdx.x - 4096;
    const int s0 = (idx & 31) * 64;
    const int bkv = idx >> 5;
    const int b = bkv >> 2, kv = bkv & 3;
    const int r = tid >> 2, cg = (tid & 3) * 16;
    const bf16_t* src = qkv + (size_t)(b * 2048 + s0 + r) * 1536 + 1280 + kv * 64 + cg;
    bf16x8 v0 = *reinterpret_cast<const bf16x8*>(src);
    bf16x8 v1 = *reinterpret_cast<const bf16x8*>(src + 8);
#pragma unroll
    for (int j = 0; j < 8; ++j) {
      t[r][cg + j] = (float)v0[j];
      t[r][cg + 8 + j] = (float)v1[j];
    }
    __syncthreads();
    const int dl = tid >> 4;
    const int sl = (tid & 15) * 4;
    const int kt = (s0 >> 5) + (sl >> 5);
    const int p0 = (sl & 16) + ((sl >> 2) & 1) * 8 + ((sl >> 3) & 1) * 4;
#pragma unroll
    for (int p = 0; p < 4; ++p) {
      const int d = dl + p * 16;
      bf16x4 o = { (bf16_t)t[sl + 0][d], (bf16_t)t[sl + 1][d],
                   (bf16_t)t[sl + 2][d], (bf16_t)t[sl + 3][d] };
      *reinterpret_cast<bf16x4*>(vt + (size_t)bkv * 131072 + (size_t)kt * 2048 + d * 32 + p0) = o;
    }
  }
}

// ---------------- Flash attention, swapped-QK 32x32, 2-wave k-split --------------
// R13/R17-proven: STATIC softmax max + ZERO-SHUFFLE PV (k-perm V), plain-add merge.
__global__ __launch_bounds__(256, 4) void attn_k(const bf16_t* __restrict__ qn,
                                                 const bf16_t* __restrict__ kn,
                                                 const bf16_t* __restrict__ vt,
                                                 bf16_t* __restrict__ ao) {
  constexpr int S = 2048, D = 64, H = 16, KV = 4, WIN = 512;
  const int bkv = blockIdx.x;                     // 0..7 -> XCD selector
  const int b = bkv >> 2, kv = bkv & 3;
  const int h = kv * 4 + blockIdx.z;
  const int wid = threadIdx.x >> 6;
  const int pair = wid >> 1;
  const int kh = wid & 1;
  const int qblk = blockIdx.y * 2 + pair;
  const int lane = threadIdx.x & 63;
  const int c = lane & 31;                        // q for P, d for O
  const int hi = lane >> 5;
  const int qbase = qblk * 32;
  const int q = qbase + c;

  __shared__ float lsh[2][2][32];                 // [pair][kh][q] row sums
  __shared__ float accbuf[2][64][33];             // [pair][lane][r], +1 pad

  const bf16_t* qp = qn + ((size_t)(b * H + h) * S + q) * D + hi * 8;
  bf16x8 qf[4];
#pragma unroll
  for (int cd = 0; cd < 4; ++cd) qf[cd] = *reinterpret_cast<const bf16x8*>(qp + cd * 16);

  const bf16_t* kb = kn + (size_t)bkv * S * D;
  const bf16_t* vb = vt + (size_t)bkv * 131072;   // [kt][d][kk-perm] tiles

  const float L2E = 1.4426950408889634f;
  const float MSTAT = 8.0f * L2E;                 // static max
  const float c1 = L2E / 8.0f;
  const float c2 = exp2f(-0.5f * (float)h) * L2E;

  f32x16 acc0 = {}, acc1 = {};
  float l_run = 0.0f;

  const int ktTop = qbase >> 5;
  const int kt0 = (qbase >= WIN) ? ((qbase - WIN) >> 5) : 0;

  for (int kt = ktTop - kh; kt >= kt0; kt -= 2) {
    const int k0 = kt << 5;
    const bf16_t* kp = kb + (((size_t)k0 + c) << 6) + hi * 8;
    f32x16 sfa = {};
    __builtin_amdgcn_s_setprio(1);
#pragma unroll
    for (int cd = 0; cd < 4; ++cd) {
      bf16x8 kf = *reinterpret_cast<const bf16x8*>(kp + cd * 16);
      sfa = mfma32(kf, qf[cd], sfa);
    }
    __builtin_amdgcn_s_setprio(0);
    const bool edge = (kt == ktTop) | (k0 + WIN < qbase + 32);
    const float bbm = fmaf(c2, (float)(k0 + 4 * hi - q), -MSTAT);
    float rs = 0.0f;
    unsigned w[8];
#pragma unroll
    for (int i = 0; i < 8; ++i) {
      float e2[2];
#pragma unroll
      for (int j = 0; j < 2; ++j) {
        const int r = 2 * i + j;
        const float koff = (float)((r & 3) + 8 * (r >> 2));
        if (edge) {
          const int rel = k0 + (int)koff + 4 * hi - q;
          float tv = fmaf(sfa[r], c1, fmaf((float)rel, c2, -MSTAT));
          tv = (rel > 0 || rel < -WIN) ? -3.0e38f : tv;
          e2[j] = exp2f(tv);
        } else {
          e2[j] = exp2f(fmaf(sfa[r], c1, fmaf(koff, c2, bbm)));
        }
      }
      rs += e2[0] + e2[1];
      union { bf16_t hh[2]; unsigned u; } pk;
      pk.hh[0] = (bf16_t)e2[0]; pk.hh[1] = (bf16_t)e2[1];
      w[i] = pk.u;
    }
    rs += __shfl_xor(rs, 32, 64);                 // cross-half row sum
    l_run += rs;
    // ---- zero-shuffle P A-fragments ----
    union { unsigned u[4]; bf16x8 v; } pa0, pa1;
    pa0.u[0] = w[0]; pa0.u[1] = w[1]; pa0.u[2] = w[2]; pa0.u[3] = w[3];
    pa1.u[0] = w[4]; pa1.u[1] = w[5]; pa1.u[2] = w[6]; pa1.u[3] = w[7];
    // ---- PV: V loaded late (proven no-spill placement) ----
    const bf16_t* vp = vb + ((size_t)kt << 11) + c * 32 + hi * 8;
    bf16x8 v00 = *reinterpret_cast<const bf16x8*>(vp);
    bf16x8 v01 = *reinterpret_cast<const bf16x8*>(vp + 16);
    bf16x8 v10 = *reinterpret_cast<const bf16x8*>(vp + 1024);
    bf16x8 v11 = *reinterpret_cast<const bf16x8*>(vp + 1024 + 16);
    __builtin_amdgcn_s_setprio(1);
    acc0 = mfma32(pa0.v, v00, acc0);
    acc0 = mfma32(pa1.v, v01, acc0);
    acc1 = mfma32(pa0.v, v10, acc1);
    acc1 = mfma32(pa1.v, v11, acc1);
    __builtin_amdgcn_s_setprio(0);
  }

  lsh[pair][kh][c] = l_run;
  if (kh == 1) {
#pragma unroll
    for (int r = 0; r < 16; ++r) {
      accbuf[pair][lane][r] = acc0[r];
      accbuf[pair][lane][r + 16] = acc1[r];
    }
  }
  __syncthreads();
  if (kh == 0) {
    const float l_tot = l_run + lsh[pair][1][c];
#pragma unroll
    for (int r = 0; r < 16; ++r) {
      acc0[r] += accbuf[pair][lane][r];
      acc1[r] += accbuf[pair][lane][r + 16];
    }
#pragma unroll
    for (int r = 0; r < 16; ++r) {
      const int qi = (r & 3) + 8 * (r >> 2) + 4 * hi;
      const float lr = __shfl(l_tot, qi, 64);
      const float inv = 1.0f / lr;
      bf16_t* op = ao + ((size_t)(b * S + qbase + qi)) * 1024 + h * 64 + c;
      op[0]  = (bf16_t)(acc0[r] * inv);
      op[32] = (bf16_t)(acc1[r] * inv);
    }
  }
}

extern "C" void kernel_launch(void* const* d_in, const int* in_sizes, int n_in,
                              void* d_out, int out_size, void* d_ws, size_t ws_size,
                              hipStream_t stream) {
  const float* features = (const float*)d_in[0];
  const float* wq = (const float*)d_in[1];
  const float* wk = (const float*)d_in[2];
  const float* wv = (const float*)d_in[3];
  const float* wo = (const float*)d_in[4];
  const float* qw = (const float*)d_in[5];
  const float* kw = (const float*)d_in[6];
  float* out = (float*)d_out;

  bf16_t* Xbf  = (bf16_t*)d_ws;                   // 4096*1024
  bf16_t* Wqkv = Xbf + 4096 * 1024;               // 1536*1024
  bf16_t* Wo   = Wqkv + 1536 * 1024;              // 1024*1024
  bf16_t* QKVr = Wo + 1024 * 1024;                // 4096*1536 bf16
  bf16_t* Qn   = QKVr + 4096 * 1536;              // [2,16,2048,64]
  bf16_t* Kn   = Qn + 2 * 16 * 2048 * 64;         // [2,4,2048,64]
  bf16_t* Vt   = Kn + 2 * 4 * 2048 * 64;          // [8][64][64][32]-tiled, k-perm
  bf16_t* Ao   = Vt + 2 * 4 * 64 * 2048;          // [4096,1024]

  cast_all_k<<<6656, 256, 0, stream>>>(features, wq, wk, wv, wo, Xbf, Wqkv, Wo);
  gemm_bt<128, bf16_t><<<dim3(12, 32), 256, 0, stream>>>(Xbf, Wqkv, QKVr, 4096, 1536, 1024);
  norm_trans_k<<<4352, 256, 0, stream>>>(QKVr, qw, kw, Qn, Kn, Vt);
  attn_k<<<dim3(8, 32, 4), 256, 0, stream>>>(Qn, Kn, Vt, Ao);
  gemm_bt<128, float><<<dim3(8, 32), 256, 0, stream>>>(Ao, Wo, out, 4096, 1024, 1024);
}

// Round 20
// 86.280 us; speedup vs baseline: 1.0746x; 1.0746x over previous
//
#include <hip/hip_runtime.h>
#include <hip/hip_bf16.h>

typedef __bf16 bf16_t;
typedef bf16_t bf16x8 __attribute__((ext_vector_type(8)));
typedef bf16_t bf16x4 __attribute__((ext_vector_type(4)));
typedef float  f32x4  __attribute__((ext_vector_type(4)));
typedef float  f32x16 __attribute__((ext_vector_type(16)));

__device__ __forceinline__ f32x4 mfma16(bf16x8 a, bf16x8 b, f32x4 c) {
  return __builtin_amdgcn_mfma_f32_16x16x32_bf16(a, b, c, 0, 0, 0);
}
__device__ __forceinline__ f32x16 mfma32(bf16x8 a, bf16x8 b, f32x16 c) {
  return __builtin_amdgcn_mfma_f32_32x32x16_bf16(a, b, c, 0, 0, 0);
}

// ---------------- fused cast f32 -> bf16 for all 5 tensors ----------------
__global__ __launch_bounds__(256) void cast_all_k(const float* __restrict__ f,
                                                  const float* __restrict__ wq,
                                                  const float* __restrict__ wk,
                                                  const float* __restrict__ wv,
                                                  const float* __restrict__ wo,
                                                  bf16_t* __restrict__ Xbf,
                                                  bf16_t* __restrict__ Wqkv,
                                                  bf16_t* __restrict__ Wo) {
  int i = blockIdx.x * 256 + threadIdx.x;
  const float* src; bf16_t* dst; int off;
  if (i < 1048576)      { src = f;  dst = Xbf;                 off = 0; }
  else if (i < 1310720) { src = wq; dst = Wqkv;                off = 1048576; }
  else if (i < 1376256) { src = wk; dst = Wqkv + 1024 * 1024;  off = 1310720; }
  else if (i < 1441792) { src = wv; dst = Wqkv + 1280 * 1024;  off = 1376256; }
  else if (i < 1703936) { src = wo; dst = Wo;                  off = 1441792; }
  else return;
  int j = i - off;
  float4 v = reinterpret_cast<const float4*>(src)[j];
  bf16x4 o = { (bf16_t)v.x, (bf16_t)v.y, (bf16_t)v.z, (bf16_t)v.w };
  reinterpret_cast<bf16x4*>(dst)[j] = o;
}

// ---------------- GEMM: C[M,N] = A[M,K] * B[N,K]^T, bf16 in, CT out -------------
// BM x 128 tile, BK=64, 4 waves, 16x16x32 MFMA, double-buffered LDS with
// COUNTED-vmcnt pipeline (T4): loads never drained to 0 inside the loop.
// BM=64: 3 blocks/CU — best measured tile for these shapes (R17 vs R19).
template<int BM, typename CT>
__global__ __launch_bounds__(256) void gemm_bt(const bf16_t* __restrict__ A,
                                               const bf16_t* __restrict__ B,
                                               CT* __restrict__ C,
                                               int M, int N, int K) {
  constexpr int MR = BM / 32;                     // acc rows per wave
  __shared__ __align__(16) unsigned short sA[2][BM * 64];
  __shared__ __align__(16) unsigned short sB[2][128 * 64];
  const int tid = threadIdx.x;
  const int lane = tid & 63;
  const int wid = tid >> 6;
  const int wm = wid >> 1, wn = wid & 1;
  const int lr = lane & 15, lg = lane >> 4;
  const int m0 = blockIdx.y * BM, n0 = blockIdx.x * 128;

  f32x4 acc[MR][4] = {};

  auto STAGE = [&](int buf, int k0) {             // 6 global_load_lds per wave
#pragma unroll
    for (int r = 0; r < BM / 32; ++r) {
      int e = r * 2048 + tid * 8;
      int row = e >> 6;
      int cc = ((e >> 3) & 7) ^ (row & 7);
      const bf16_t* ga = A + (size_t)(m0 + row) * K + k0 + cc * 8;
      __builtin_amdgcn_global_load_lds(
          (const __attribute__((address_space(1))) void*)ga,
          (__attribute__((address_space(3))) void*)(&sA[buf][r * 2048 + wid * 512]), 16, 0, 0);
    }
#pragma unroll
    for (int r = 0; r < 4; ++r) {
      int e = r * 2048 + tid * 8;
      int row = e >> 6;
      int cc = ((e >> 3) & 7) ^ (row & 7);
      const bf16_t* gb = B + (size_t)(n0 + row) * K + k0 + cc * 8;
      __builtin_amdgcn_global_load_lds(
          (const __attribute__((address_space(1))) void*)gb,
          (__attribute__((address_space(3))) void*)(&sB[buf][r * 2048 + wid * 512]), 16, 0, 0);
    }
  };

  const int nt = K >> 6;
  STAGE(0, 0);
  if (nt > 1) STAGE(1, 64);
  for (int t = 0; t < nt; ++t) {
    if (t < nt - 1) asm volatile("s_waitcnt vmcnt(6)" ::: "memory");
    else            asm volatile("s_waitcnt vmcnt(0)" ::: "memory");
    asm volatile("s_barrier" ::: "memory");       // STAGE(t) visible block-wide
    __builtin_amdgcn_sched_barrier(0);
    const int cur = t & 1;
#pragma unroll
    for (int ks = 0; ks < 2; ++ks) {
      bf16x8 afr[MR], bfr[4];
#pragma unroll
      for (int m = 0; m < MR; ++m) {
        int row = wm * (BM / 2) + m * 16 + lr;
        int sc = (ks * 4 + lg) ^ (row & 7);
        afr[m] = *reinterpret_cast<const bf16x8*>(&sA[cur][row * 64 + sc * 8]);
      }
#pragma unroll
      for (int n = 0; n < 4; ++n) {
        int row = wn * 64 + n * 16 + lr;
        int sc = (ks * 4 + lg) ^ (row & 7);
        bfr[n] = *reinterpret_cast<const bf16x8*>(&sB[cur][row * 64 + sc * 8]);
      }
#pragma unroll
      for (int m = 0; m < MR; ++m)
#pragma unroll
        for (int n = 0; n < 4; ++n)
          acc[m][n] = mfma16(afr[m], bfr[n], acc[m][n]);
    }
    asm volatile("s_barrier" ::: "memory");       // all reads of buf cur done
    if (t + 2 < nt) STAGE(cur, (t + 2) << 6);     // refill freed buffer
  }
#pragma unroll
  for (int m = 0; m < MR; ++m)
#pragma unroll
    for (int n = 0; n < 4; ++n) {
      int row = m0 + wm * (BM / 2) + m * 16 + lg * 4;
      int col = n0 + wn * 64 + n * 16 + lr;
#pragma unroll
      for (int r2 = 0; r2 < 4; ++r2)
        C[(size_t)(row + r2) * N + col] = (CT)acc[m][n][r2];
    }
}

// ---------------- merged RMSNorm + V-transpose (independent consumers of QKVr) ---
__global__ __launch_bounds__(256) void norm_trans_k(const bf16_t* __restrict__ qkv,
                                                    const float* __restrict__ qw,
                                                    const float* __restrict__ kw,
                                                    bf16_t* __restrict__ qn,
                                                    bf16_t* __restrict__ kn,
                                                    bf16_t* __restrict__ vt) {
  __shared__ float t[64][65];
  const int tid = threadIdx.x;
  if (blockIdx.x < 4096) {
    const int row = blockIdx.x;
    const int b = row >> 11, s = row & 2047;
    const bf16_t* rp = qkv + (size_t)row * 1536;
    bf16x4 qb = *reinterpret_cast<const bf16x4*>(rp + tid * 4);
    float q0 = (float)qb[0], q1 = (float)qb[1], q2 = (float)qb[2], q3 = (float)qb[3];
    float kv1 = (float)rp[1024 + tid];
    float sq = q0 * q0 + q1 * q1 + q2 * q2 + q3 * q3;
    float sk = kv1 * kv1;
#pragma unroll
    for (int d = 1; d < 64; d <<= 1) {
      sq += __shfl_xor(sq, d, 64);
      sk += __shfl_xor(sk, d, 64);
    }
    if ((tid & 63) == 0) { t[0][tid >> 6] = sq; t[0][4 + (tid >> 6)] = sk; }
    __syncthreads();
    sq = t[0][0] + t[0][1] + t[0][2] + t[0][3];
    sk = t[0][4] + t[0][5] + t[0][6] + t[0][7];
    const float rq = rsqrtf(sq * (1.0f / 1024.0f) + 1e-6f);
    const float rk = rsqrtf(sk * (1.0f / 256.0f) + 1e-6f);
    float4 w4 = *reinterpret_cast<const float4*>(qw + tid * 4);
    const int c = tid * 4, hh = c >> 6, d0 = c & 63;
    bf16x4 o = { (bf16_t)(q0 * rq * w4.x), (bf16_t)(q1 * rq * w4.y),
                 (bf16_t)(q2 * rq * w4.z), (bf16_t)(q3 * rq * w4.w) };
    *reinterpret_cast<bf16x4*>(qn + ((size_t)((b * 16 + hh) * 2048 + s)) * 64 + d0) = o;
    const int kvh = tid >> 6, dk = tid & 63;
    kn[((size_t)((b * 4 + kvh) * 2048 + s)) * 64 + dk] = (bf16_t)(kv1 * rk * kw[tid]);
  } else {
    const int idx = blockIdx.x - 4096;
    const int s0 = (idx & 31) * 64;
    const int bkv = idx >> 5;
    const int b = bkv >> 2, kv = bkv & 3;
    const int r = tid >> 2, cg = (tid & 3) * 16;
    const bf16_t* src = qkv + (size_t)(b * 2048 + s0 + r) * 1536 + 1280 + kv * 64 + cg;
    bf16x8 v0 = *reinterpret_cast<const bf16x8*>(src);
    bf16x8 v1 = *reinterpret_cast<const bf16x8*>(src + 8);
#pragma unroll
    for (int j = 0; j < 8; ++j) {
      t[r][cg + j] = (float)v0[j];
      t[r][cg + 8 + j] = (float)v1[j];
    }
    __syncthreads();
    const int dl = tid >> 4;
    const int sl = (tid & 15) * 4;
    const int kt = (s0 >> 5) + (sl >> 5);
    const int p0 = (sl & 16) + ((sl >> 2) & 1) * 8 + ((sl >> 3) & 1) * 4;
#pragma unroll
    for (int p = 0; p < 4; ++p) {
      const int d = dl + p * 16;
      bf16x4 o = { (bf16_t)t[sl + 0][d], (bf16_t)t[sl + 1][d],
                   (bf16_t)t[sl + 2][d], (bf16_t)t[sl + 3][d] };
      *reinterpret_cast<bf16x4*>(vt + (size_t)bkv * 131072 + (size_t)kt * 2048 + d * 32 + p0) = o;
    }
  }
}

// ---------------- Flash attention, swapped-QK 32x32, 2-wave k-split --------------
// R13/R17-proven: STATIC softmax max + ZERO-SHUFFLE PV (k-perm V), plain-add merge.
__global__ __launch_bounds__(256, 4) void attn_k(const bf16_t* __restrict__ qn,
                                                 const bf16_t* __restrict__ kn,
                                                 const bf16_t* __restrict__ vt,
                                                 bf16_t* __restrict__ ao) {
  constexpr int S = 2048, D = 64, H = 16, KV = 4, WIN = 512;
  const int bkv = blockIdx.x;                     // 0..7 -> XCD selector
  const int b = bkv >> 2, kv = bkv & 3;
  const int h = kv * 4 + blockIdx.z;
  const int wid = threadIdx.x >> 6;
  const int pair = wid >> 1;
  const int kh = wid & 1;
  const int qblk = blockIdx.y * 2 + pair;
  const int lane = threadIdx.x & 63;
  const int c = lane & 31;                        // q for P, d for O
  const int hi = lane >> 5;
  const int qbase = qblk * 32;
  const int q = qbase + c;

  __shared__ float lsh[2][2][32];                 // [pair][kh][q] row sums
  __shared__ float accbuf[2][64][33];             // [pair][lane][r], +1 pad

  const bf16_t* qp = qn + ((size_t)(b * H + h) * S + q) * D + hi * 8;
  bf16x8 qf[4];
#pragma unroll
  for (int cd = 0; cd < 4; ++cd) qf[cd] = *reinterpret_cast<const bf16x8*>(qp + cd * 16);

  const bf16_t* kb = kn + (size_t)bkv * S * D;
  const bf16_t* vb = vt + (size_t)bkv * 131072;   // [kt][d][kk-perm] tiles

  const float L2E = 1.4426950408889634f;
  const float MSTAT = 8.0f * L2E;                 // static max
  const float c1 = L2E / 8.0f;
  const float c2 = exp2f(-0.5f * (float)h) * L2E;

  f32x16 acc0 = {}, acc1 = {};
  float l_run = 0.0f;

  const int ktTop = qbase >> 5;
  const int kt0 = (qbase >= WIN) ? ((qbase - WIN) >> 5) : 0;

  for (int kt = ktTop - kh; kt >= kt0; kt -= 2) {
    const int k0 = kt << 5;
    const bf16_t* kp = kb + (((size_t)k0 + c) << 6) + hi * 8;
    f32x16 sfa = {};
    __builtin_amdgcn_s_setprio(1);
#pragma unroll
    for (int cd = 0; cd < 4; ++cd) {
      bf16x8 kf = *reinterpret_cast<const bf16x8*>(kp + cd * 16);
      sfa = mfma32(kf, qf[cd], sfa);
    }
    __builtin_amdgcn_s_setprio(0);
    const bool edge = (kt == ktTop) | (k0 + WIN < qbase + 32);
    const float bbm = fmaf(c2, (float)(k0 + 4 * hi - q), -MSTAT);
    float rs = 0.0f;
    unsigned w[8];
#pragma unroll
    for (int i = 0; i < 8; ++i) {
      float e2[2];
#pragma unroll
      for (int j = 0; j < 2; ++j) {
        const int r = 2 * i + j;
        const float koff = (float)((r & 3) + 8 * (r >> 2));
        if (edge) {
          const int rel = k0 + (int)koff + 4 * hi - q;
          float tv = fmaf(sfa[r], c1, fmaf((float)rel, c2, -MSTAT));
          tv = (rel > 0 || rel < -WIN) ? -3.0e38f : tv;
          e2[j] = exp2f(tv);
        } else {
          e2[j] = exp2f(fmaf(sfa[r], c1, fmaf(koff, c2, bbm)));
        }
      }
      rs += e2[0] + e2[1];
      union { bf16_t hh[2]; unsigned u; } pk;
      pk.hh[0] = (bf16_t)e2[0]; pk.hh[1] = (bf16_t)e2[1];
      w[i] = pk.u;
    }
    rs += __shfl_xor(rs, 32, 64);                 // cross-half row sum
    l_run += rs;
    // ---- zero-shuffle P A-fragments ----
    union { unsigned u[4]; bf16x8 v; } pa0, pa1;
    pa0.u[0] = w[0]; pa0.u[1] = w[1]; pa0.u[2] = w[2]; pa0.u[3] = w[3];
    pa1.u[0] = w[4]; pa1.u[1] = w[5]; pa1.u[2] = w[6]; pa1.u[3] = w[7];
    // ---- PV: V loaded late (proven no-spill placement) ----
    const bf16_t* vp = vb + ((size_t)kt << 11) + c * 32 + hi * 8;
    bf16x8 v00 = *reinterpret_cast<const bf16x8*>(vp);
    bf16x8 v01 = *reinterpret_cast<const bf16x8*>(vp + 16);
    bf16x8 v10 = *reinterpret_cast<const bf16x8*>(vp + 1024);
    bf16x8 v11 = *reinterpret_cast<const bf16x8*>(vp + 1024 + 16);
    __builtin_amdgcn_s_setprio(1);
    acc0 = mfma32(pa0.v, v00, acc0);
    acc0 = mfma32(pa1.v, v01, acc0);
    acc1 = mfma32(pa0.v, v10, acc1);
    acc1 = mfma32(pa1.v, v11, acc1);
    __builtin_amdgcn_s_setprio(0);
  }

  lsh[pair][kh][c] = l_run;
  if (kh == 1) {
#pragma unroll
    for (int r = 0; r < 16; ++r) {
      accbuf[pair][lane][r] = acc0[r];
      accbuf[pair][lane][r + 16] = acc1[r];
    }
  }
  __syncthreads();
  if (kh == 0) {
    const float l_tot = l_run + lsh[pair][1][c];
#pragma unroll
    for (int r = 0; r < 16; ++r) {
      acc0[r] += accbuf[pair][lane][r];
      acc1[r] += accbuf[pair][lane][r + 16];
    }
#pragma unroll
    for (int r = 0; r < 16; ++r) {
      const int qi = (r & 3) + 8 * (r >> 2) + 4 * hi;
      const float lr = __shfl(l_tot, qi, 64);
      const float inv = 1.0f / lr;
      bf16_t* op = ao + ((size_t)(b * S + qbase + qi)) * 1024 + h * 64 + c;
      op[0]  = (bf16_t)(acc0[r] * inv);
      op[32] = (bf16_t)(acc1[r] * inv);
    }
  }
}

extern "C" void kernel_launch(void* const* d_in, const int* in_sizes, int n_in,
                              void* d_out, int out_size, void* d_ws, size_t ws_size,
                              hipStream_t stream) {
  const float* features = (const float*)d_in[0];
  const float* wq = (const float*)d_in[1];
  const float* wk = (const float*)d_in[2];
  const float* wv = (const float*)d_in[3];
  const float* wo = (const float*)d_in[4];
  const float* qw = (const float*)d_in[5];
  const float* kw = (const float*)d_in[6];
  float* out = (float*)d_out;

  bf16_t* Xbf  = (bf16_t*)d_ws;                   // 4096*1024
  bf16_t* Wqkv = Xbf + 4096 * 1024;               // 1536*1024
  bf16_t* Wo   = Wqkv + 1536 * 1024;              // 1024*1024
  bf16_t* QKVr = Wo + 1024 * 1024;                // 4096*1536 bf16
  bf16_t* Qn   = QKVr + 4096 * 1536;              // [2,16,2048,64]
  bf16_t* Kn   = Qn + 2 * 16 * 2048 * 64;         // [2,4,2048,64]
  bf16_t* Vt   = Kn + 2 * 4 * 2048 * 64;          // [8][64][64][32]-tiled, k-perm
  bf16_t* Ao   = Vt + 2 * 4 * 64 * 2048;          // [4096,1024]

  cast_all_k<<<6656, 256, 0, stream>>>(features, wq, wk, wv, wo, Xbf, Wqkv, Wo);
  gemm_bt<64, bf16_t><<<dim3(12, 64), 256, 0, stream>>>(Xbf, Wqkv, QKVr, 4096, 1536, 1024);
  norm_trans_k<<<4352, 256, 0, stream>>>(QKVr, qw, kw, Qn, Kn, Vt);
  attn_k<<<dim3(8, 32, 4), 256, 0, stream>>>(Qn, Kn, Vt, Ao);
  gemm_bt<64, float><<<dim3(8, 64), 256, 0, stream>>>(Ao, Wo, out, 4096, 1024, 1024);
}